// Round 5
// baseline (204.944 us; speedup 1.0000x reference)
//
#include <hip/hip_runtime.h>

// RandomShiftsAug: out[n,c,h,w] = x[n,c, clamp(h+sy,0,83), clamp(w+sx,0,83)],
// sx,sy = shift[n] - 4 in [-4,4], uniform per image. Pure edge-clamped gather.
//
// R7 -> R8: asm-volatile-forced load batch (the compiler defeated both prior
// attempts at deep MLP).
//   Post-mortem R7: sched_barrier(0) did NOT survive -- VGPR_Count still 24
//   (7 live f4u quads need >=28), dur/HBM identical to R6 (70us, 2.43 TB/s).
//   Consumers' data deps only order against load ISSUE; pure-VALU selects
//   carry no chain, so LLVM re-sank loads to uses => effective MLP~2 again.
//   Seven source structures have compiled to this same memory shape, all
//   59-73us, while write-only fills do 6.6 TB/s. Latency/MLP theory remains
//   untested -> test it with schedules the compiler CANNOT touch:
//   - 7x asm volatile global_load_dwordx4 (SGPR plane base + 32b voffset,
//     offsets < 28KB), issued back-to-back: 7KB in flight per wave.
//   - one asm s_waitcnt vmcnt(0) with all 7 result quads as "+v" operands:
//     every consumer data-depends on the WAIT, not just the load issue.
//   - sched_barrier(0) after the wait (rule #18 belt-and-suspenders).
//   - dwordx4 @ dword alignment: same lowering R6/R7 used (align(4) loads
//     under default unaligned-access-mode), both passed -> HW-validated.
// Predicted: VGPR 24 -> ~48-64 (PROOF the forcing worked; check first).
// If MLP theory right: dur 70 -> ~38-45us, hbm_gbps -> ~4000+, bench ~175.
// Falsifier: VGPR>=48 but dur 68-72 => latency theory dead, declare
// structural cap next round.

#define HW 84
#define PADV 4
#define PLANE (HW * HW)      // 7056 floats per (n,c) plane
#define PF4   (PLANE / 4)    // 1764 float4 per plane
#define NTHR  256
#define K     7              // ceil(1764/256): float4s per thread

typedef float f32x4 __attribute__((ext_vector_type(4)));

__device__ __forceinline__ float pick(f32x4 v, int idx) {
    // idx in [0,3] -> cndmask chain, constant extracts only (rule #20)
    return (idx < 1) ? v[0] : (idx < 2) ? v[1] : (idx < 3) ? v[2] : v[3];
}

__global__ __launch_bounds__(NTHR)
void shift_aug_kernel(const float* __restrict__ x,
                      const int* __restrict__ shift,
                      float* __restrict__ out) {
    const int tid = threadIdx.x;
    const int b   = blockIdx.x;        // plane id = n*4 + c (planes linear)
    const int n   = b >> 2;

    const int sx = shift[2 * n]     - PADV;   // uniform -> SGPR
    const int sy = shift[2 * n + 1] - PADV;

    const float* plane  = x + (size_t)b * PLANE;   // uniform -> SGPR pair
    float* __restrict__ oplane = out + (size_t)b * PLANE;

    // ---- addresses (byte voffsets within plane) + select corrections ----
    int voff[K];
    int dsel[K];
    #pragma unroll
    for (int i = 0; i < K; ++i) {
        const int g   = tid + NTHR * i;             // output float4 index
        const int gi  = (g < PF4) ? g : (PF4 - 1);  // clamp tail (load only)
        const int row = gi / 21;                    // compiler magic-mul
        const int tx  = gi - row * 21;
        const int srow = min(max(row + sy, 0), HW - 1);
        const int cb   = 4 * tx + sx;               // wanted start col, may be OOB
        const int B    = min(max(cb, 0), HW - 4);   // clamped 4-valid load base
        voff[i] = 4 * (srow * HW + B);              // 0 .. 28208 (+16B <= 28224)
        dsel[i] = cb - B;                           // in [-4,4]; 0 for interior
    }

    // ---- forced batch: 7 loads in flight, compiler cannot reorder/shrink ----
    f32x4 L[K];
    #pragma unroll
    for (int i = 0; i < K; ++i)
        asm volatile("global_load_dwordx4 %0, %1, %2"
                     : "=v"(L[i])
                     : "v"(voff[i]), "s"(plane));

    // Single drain; every L[i] is a "+v" operand so all consumers data-depend
    // on the wait itself, not merely on the load issue.
    asm volatile("s_waitcnt vmcnt(0)"
                 : "+v"(L[0]), "+v"(L[1]), "+v"(L[2]), "+v"(L[3]),
                   "+v"(L[4]), "+v"(L[5]), "+v"(L[6])
                 :
                 : "memory");
    __builtin_amdgcn_sched_barrier(0);

    // ---- per-element select + aligned store ----
    #pragma unroll
    for (int i = 0; i < K; ++i) {
        const int d = dsel[i];
        float4 o;
        o.x = pick(L[i], min(max(d,     0), 3));
        o.y = pick(L[i], min(max(d + 1, 0), 3));
        o.z = pick(L[i], min(max(d + 2, 0), 3));
        o.w = pick(L[i], min(max(d + 3, 0), 3));

        const int g = tid + NTHR * i;
        if (i < K - 1) {
            ((float4*)oplane)[g] = o;               // g <= 1535 < PF4 always
        } else if (g < PF4) {
            ((float4*)oplane)[g] = o;               // masked tail (228/256 active)
        }
    }
}

extern "C" void kernel_launch(void* const* d_in, const int* in_sizes, int n_in,
                              void* d_out, int out_size, void* d_ws, size_t ws_size,
                              hipStream_t stream) {
    const float* x     = (const float*)d_in[0];
    const int*   shift = (const int*)d_in[1];
    float*       out   = (float*)d_out;

    dim3 block(NTHR, 1, 1);
    dim3 grid(4096, 1, 1);     // one (n,c) plane per block, linear in memory
    shift_aug_kernel<<<grid, block, 0, stream>>>(x, shift, out);
}